// Round 10
// baseline (90.467 us; speedup 1.0000x reference)
//
#include <hip/hip_runtime.h>

#define BATCH   1024
#define ASZ     256
#define EDIM    200
#define RDIM    200
#define HDIM    400
#define ACTDIM  400   // E+R
#define INDIM   800   // E+H+R
#define NRELS   500

typedef __attribute__((ext_vector_type(8))) short short8v;   // 8 bf16 (4 VGPR)
typedef __attribute__((ext_vector_type(4))) float float4v;   // MFMA acc
typedef unsigned short u16;

__device__ __forceinline__ u16 f2bf(float f) {               // RNE fp32->bf16
    union { float f; unsigned u; } v; v.f = f;
    unsigned r = v.u + 0x7FFFu + ((v.u >> 16) & 1u);
    return (u16)(r >> 16);
}

// ---------------------------------------------------------------------------
// Shared MFMA GEMM body: C = A[M,K] @ B^T (B stored [N][K]).
// 256 thr = 4 waves; 64x64 tile; wave -> 32x32 (2x2 16x16x32 frags).
// Software-prefetched staging (step s+1 loads issue under step s's MFMA).
// ABF: 0 = A fp32 [M][K]; 1 = A bf16 [M][K];
//      2 = A is 4 fp32 split-K slabs [4][M][K]: stage = relu(sum+biasA) -> bf16
//          (identical arithmetic to the old k_reduce2 epilogue).
// CT=1: fp32 partials to Cp slab z.  CT=2: bf16 transposed write to CTout.
// CT=3: bias (+relu) -> fp32 Cf AND bf16 Cb.   CT=4: bias -> fp32 Cf only.
// GAT=1: A is the virtual fp32 concat [ent[e]|H|rel[q]] (chunk-aligned).
// ---------------------------------------------------------------------------
template<int ABF, int BBF, int CT, int GAT, int RELU>
__device__ __forceinline__ void mgemm_body(
    const void* __restrict__ A, const void* __restrict__ B,
    const float* __restrict__ biasA,
    float* __restrict__ Cp, u16* __restrict__ CTout, int ldct,
    const float* __restrict__ bias, float* __restrict__ Cf, u16* __restrict__ Cb,
    int M, int N, int K, int bn, int bm, int z, int nz,
    const int* e_s, const int* q_s,
    const float* __restrict__ Hm, const float* __restrict__ ent,
    const float* __restrict__ rel,
    short* As, short* Bs, int t)
{
    const int tot = (K + 31) >> 5;
    const int s0 = (z * tot) / nz, s1 = ((z + 1) * tot) / nz;

    const int lane = t & 63, w = t >> 6;
    const int l15 = lane & 15, l4 = lane >> 4;
    const int wr = (w >> 1) * 32, wc = (w & 1) * 32;

    const int row = t >> 2;          // staging row 0..63
    const int kc  = (t & 3) * 8;     // staging k-chunk

    auto loadA = [&](int s) -> uint4 {
        const int gk = (s << 5) + kc;
        __attribute__((aligned(16))) u16 v[8];
        if (GAT) {
            const float* p;
            if (gk < EDIM)              p = ent + (long)e_s[row] * EDIM + gk;
            else if (gk < EDIM + HDIM)  p = Hm  + (long)(bm + row) * HDIM + (gk - EDIM);
            else                        p = rel + (long)q_s[row] * RDIM + (gk - EDIM - HDIM);
            float4 f0 = *(const float4*)p;
            float4 f1 = *(const float4*)(p + 4);
            v[0]=f2bf(f0.x); v[1]=f2bf(f0.y); v[2]=f2bf(f0.z); v[3]=f2bf(f0.w);
            v[4]=f2bf(f1.x); v[5]=f2bf(f1.y); v[6]=f2bf(f1.z); v[7]=f2bf(f1.w);
            return *(uint4*)v;
        }
        const int gr = bm + row;
        if (ABF == 2) {
            // 4-slab reduce + bias + relu + cvt (== old k_reduce2<1,1>)
            const long sl = (long)M * K;
            const float* p0 = (const float*)A + (long)gr * K + gk;
            float4 a0 = *(const float4*)p0,        a1 = *(const float4*)(p0 + 4);
            float4 b0 = *(const float4*)(p0 + sl), b1 = *(const float4*)(p0 + sl + 4);
            float4 c0 = *(const float4*)(p0+2*sl), c1 = *(const float4*)(p0 + 2*sl + 4);
            float4 d0 = *(const float4*)(p0+3*sl), d1 = *(const float4*)(p0 + 3*sl + 4);
            float4 e0 = *(const float4*)(biasA + gk);
            float4 e1 = *(const float4*)(biasA + gk + 4);
            float s0v = fmaxf(a0.x + b0.x + c0.x + d0.x + e0.x, 0.f);
            float s1v = fmaxf(a0.y + b0.y + c0.y + d0.y + e0.y, 0.f);
            float s2v = fmaxf(a0.z + b0.z + c0.z + d0.z + e0.z, 0.f);
            float s3v = fmaxf(a0.w + b0.w + c0.w + d0.w + e0.w, 0.f);
            float s4v = fmaxf(a1.x + b1.x + c1.x + d1.x + e1.x, 0.f);
            float s5v = fmaxf(a1.y + b1.y + c1.y + d1.y + e1.y, 0.f);
            float s6v = fmaxf(a1.z + b1.z + c1.z + d1.z + e1.z, 0.f);
            float s7v = fmaxf(a1.w + b1.w + c1.w + d1.w + e1.w, 0.f);
            v[0]=f2bf(s0v); v[1]=f2bf(s1v); v[2]=f2bf(s2v); v[3]=f2bf(s3v);
            v[4]=f2bf(s4v); v[5]=f2bf(s5v); v[6]=f2bf(s6v); v[7]=f2bf(s7v);
            return *(uint4*)v;
        }
        if (gr < M && gk + 8 <= K) {
            if (ABF == 1) return *(const uint4*)((const u16*)A + (long)gr * K + gk);
            const float* p = (const float*)A + (long)gr * K + gk;
            float4 f0 = *(const float4*)p;
            float4 f1 = *(const float4*)(p + 4);
            v[0]=f2bf(f0.x); v[1]=f2bf(f0.y); v[2]=f2bf(f0.z); v[3]=f2bf(f0.w);
            v[4]=f2bf(f1.x); v[5]=f2bf(f1.y); v[6]=f2bf(f1.z); v[7]=f2bf(f1.w);
            return *(uint4*)v;
        }
#pragma unroll
        for (int i = 0; i < 8; ++i) v[i] = 0;
        return *(uint4*)v;
    };
    auto loadB = [&](int s) -> uint4 {
        const int gk = (s << 5) + kc;
        const int gr = bn + row;
        __attribute__((aligned(16))) u16 v[8];
        if (gr < N && gk + 8 <= K) {
            if (BBF) return *(const uint4*)((const u16*)B + (long)gr * K + gk);
            const float* p = (const float*)B + (long)gr * K + gk;
            float4 f0 = *(const float4*)p;
            float4 f1 = *(const float4*)(p + 4);
            v[0]=f2bf(f0.x); v[1]=f2bf(f0.y); v[2]=f2bf(f0.z); v[3]=f2bf(f0.w);
            v[4]=f2bf(f1.x); v[5]=f2bf(f1.y); v[6]=f2bf(f1.z); v[7]=f2bf(f1.w);
            return *(uint4*)v;
        }
#pragma unroll
        for (int i = 0; i < 8; ++i) v[i] = 0;
        return *(uint4*)v;
    };

    float4v acc00 = {0.f,0.f,0.f,0.f}, acc01 = {0.f,0.f,0.f,0.f};
    float4v acc10 = {0.f,0.f,0.f,0.f}, acc11 = {0.f,0.f,0.f,0.f};

    uint4 ra = loadA(s0);
    uint4 rb = loadB(s0);

    for (int s = s0; s < s1; ++s) {
        *(uint4*)&As[row * 40 + kc] = ra;
        *(uint4*)&Bs[row * 40 + kc] = rb;
        __syncthreads();
        if (s + 1 < s1) {               // prefetch overlaps MFMA + barrier
            ra = loadA(s + 1);
            rb = loadB(s + 1);
        }
        short8v a0 = *(short8v*)&As[(wr      + l15) * 40 + l4 * 8];
        short8v a1 = *(short8v*)&As[(wr + 16 + l15) * 40 + l4 * 8];
        short8v b0 = *(short8v*)&Bs[(wc      + l15) * 40 + l4 * 8];
        short8v b1 = *(short8v*)&Bs[(wc + 16 + l15) * 40 + l4 * 8];
        acc00 = __builtin_amdgcn_mfma_f32_16x16x32_bf16(a0, b0, acc00, 0, 0, 0);
        acc01 = __builtin_amdgcn_mfma_f32_16x16x32_bf16(a0, b1, acc01, 0, 0, 0);
        acc10 = __builtin_amdgcn_mfma_f32_16x16x32_bf16(a1, b0, acc10, 0, 0, 0);
        acc11 = __builtin_amdgcn_mfma_f32_16x16x32_bf16(a1, b1, acc11, 0, 0, 0);
        __syncthreads();
    }

    const int rm0 = bm + wr + l4 * 4;
    const int cn0 = bn + wc + l15;
    if (CT == 1) {
        float* dst = Cp + (long)z * M * N;
#pragma unroll
        for (int r = 0; r < 4; ++r) {
            int gm0 = rm0 + r, gm1 = rm0 + 16 + r;
            if (gm0 < M) {
                if (cn0 < N)      dst[(long)gm0 * N + cn0]      = acc00[r];
                if (cn0 + 16 < N) dst[(long)gm0 * N + cn0 + 16] = acc01[r];
            }
            if (gm1 < M) {
                if (cn0 < N)      dst[(long)gm1 * N + cn0]      = acc10[r];
                if (cn0 + 16 < N) dst[(long)gm1 * N + cn0 + 16] = acc11[r];
            }
        }
    } else if (CT == 2) {
#pragma unroll
        for (int r = 0; r < 4; ++r) {
            int gm0 = rm0 + r, gm1 = rm0 + 16 + r;
            if (gm0 < M) {
                if (cn0 < N)      CTout[(long)cn0 * ldct + gm0]        = f2bf(acc00[r]);
                if (cn0 + 16 < N) CTout[(long)(cn0 + 16) * ldct + gm0] = f2bf(acc01[r]);
            }
            if (gm1 < M) {
                if (cn0 < N)      CTout[(long)cn0 * ldct + gm1]        = f2bf(acc10[r]);
                if (cn0 + 16 < N) CTout[(long)(cn0 + 16) * ldct + gm1] = f2bf(acc11[r]);
            }
        }
    } else if (CT == 3) {               // bias(+relu), dual fp32+bf16
        float bv0 = (cn0 < N)      ? bias[cn0]      : 0.f;
        float bv1 = (cn0 + 16 < N) ? bias[cn0 + 16] : 0.f;
#pragma unroll
        for (int r = 0; r < 4; ++r) {
            int gm0 = rm0 + r, gm1 = rm0 + 16 + r;
            if (gm0 < M) {
                if (cn0 < N) {
                    float v = acc00[r] + bv0;
                    if (RELU) v = fmaxf(v, 0.f);
                    Cf[(long)gm0 * N + cn0] = v;
                    Cb[(long)gm0 * N + cn0] = f2bf(v);
                }
                if (cn0 + 16 < N) {
                    float v = acc01[r] + bv1;
                    if (RELU) v = fmaxf(v, 0.f);
                    Cf[(long)gm0 * N + cn0 + 16] = v;
                    Cb[(long)gm0 * N + cn0 + 16] = f2bf(v);
                }
            }
            if (gm1 < M) {
                if (cn0 < N) {
                    float v = acc10[r] + bv0;
                    if (RELU) v = fmaxf(v, 0.f);
                    Cf[(long)gm1 * N + cn0] = v;
                    Cb[(long)gm1 * N + cn0] = f2bf(v);
                }
                if (cn0 + 16 < N) {
                    float v = acc11[r] + bv1;
                    if (RELU) v = fmaxf(v, 0.f);
                    Cf[(long)gm1 * N + cn0 + 16] = v;
                    Cb[(long)gm1 * N + cn0 + 16] = f2bf(v);
                }
            }
        }
    } else {                            // CT==4: bias -> fp32 only
        float bv0 = (cn0 < N)      ? bias[cn0]      : 0.f;
        float bv1 = (cn0 + 16 < N) ? bias[cn0 + 16] : 0.f;
#pragma unroll
        for (int r = 0; r < 4; ++r) {
            int gm0 = rm0 + r, gm1 = rm0 + 16 + r;
            if (gm0 < M) {
                if (cn0 < N)      Cf[(long)gm0 * N + cn0]      = acc00[r] + bv0;
                if (cn0 + 16 < N) Cf[(long)gm0 * N + cn0 + 16] = acc01[r] + bv1;
            }
            if (gm1 < M) {
                if (cn0 < N)      Cf[(long)gm1 * N + cn0]      = acc10[r] + bv0;
                if (cn0 + 16 < N) Cf[(long)gm1 * N + cn0 + 16] = acc11[r] + bv1;
            }
        }
    }
}

// ---------------------------------------------------------------------------
// k_mgemm kernel wrapper (grid: bn, bm, z)
// ---------------------------------------------------------------------------
template<int ABF, int BBF, int CT, int GAT, int RELU>
__global__ __launch_bounds__(256) void k_mgemm(
    const void* __restrict__ A, const void* __restrict__ B,
    const float* __restrict__ biasA,
    float* __restrict__ Cp, u16* __restrict__ CTout, int ldct,
    const float* __restrict__ bias, float* __restrict__ Cf, u16* __restrict__ Cb,
    int M, int N, int K,
    const int* __restrict__ eidx, const int* __restrict__ qidx,
    const float* __restrict__ Hm, const float* __restrict__ ent,
    const float* __restrict__ rel)
{
    __shared__ __align__(16) short As[64 * 40];
    __shared__ __align__(16) short Bs[64 * 40];
    __shared__ int e_s[64], q_s[64];
    const int t = threadIdx.x;
    const int bm = blockIdx.y * 64;
    if (GAT) {
        if (t < 64) {
            e_s[t] = eidx[bm + t];
            q_s[t] = qidx[bm + t];
        }
        __syncthreads();
    }
    mgemm_body<ABF, BBF, CT, GAT, RELU>(A, B, biasA, Cp, CTout, ldct, bias, Cf, Cb,
                                        M, N, K, blockIdx.x * 64, bm,
                                        blockIdx.z, gridDim.z,
                                        e_s, q_s, Hm, ent, rel, As, Bs, t);
}

// ---------------------------------------------------------------------------
// k_prep_all: blocks 0..324  W1[800,400] -> W1t[400,800] bf16 (transpose)
//             blocks 325..493 W2[400,400] -> W2t[400,400] bf16 (transpose)
//             blocks 494..593 BbigT rows 500..999 = [rel_bf16 | zeros]
//             block  594      bbig3 = [batt @ rel^T | zeros(500)]
//             blocks 595..650 BbigT rows 0..499 = (Watt @ rel^T)^T  (MFMA GEMM)
// ---------------------------------------------------------------------------
__global__ __launch_bounds__(256) void k_prep_all(
    const float* __restrict__ W1, const float* __restrict__ W2,
    const float* __restrict__ batt, const float* __restrict__ rel,
    const float* __restrict__ Watt,
    u16* __restrict__ W1t, u16* __restrict__ W2t,
    u16* __restrict__ BbigT, float* __restrict__ bbig3)
{
    __shared__ __align__(16) short As[64 * 40];
    __shared__ __align__(16) short Bs[64 * 40];
    __shared__ float tile[32][33];
    __shared__ float bs[200];

    int blk = blockIdx.x, t = threadIdx.x;

    if (blk < 325) {                       // W1 transpose: 25 k-tiles x 13 n-tiles
        int tk = blk / 13, tn = blk % 13;
        int k0 = tk * 32, n0 = tn * 32;
        int i = t >> 3, j4 = (t & 7) * 4;
#pragma unroll
        for (int jj = 0; jj < 4; ++jj) {
            int n = n0 + j4 + jj;
            tile[i][j4 + jj] = (n < 400) ? W1[(long)(k0 + i) * 400 + n] : 0.f;
        }
        __syncthreads();
        int o = t >> 3;
        if (n0 + o < 400) {
            ushort4 u;
            u.x = f2bf(tile[j4 + 0][o]); u.y = f2bf(tile[j4 + 1][o]);
            u.z = f2bf(tile[j4 + 2][o]); u.w = f2bf(tile[j4 + 3][o]);
            *(ushort4*)(W1t + (long)(n0 + o) * 800 + k0 + j4) = u;
        }
    } else if (blk < 494) {                // W2 transpose: 13 x 13
        int idx = blk - 325;
        int tk = idx / 13, tn = idx % 13;
        int k0 = tk * 32, n0 = tn * 32;
        int i = t >> 3, j4 = (t & 7) * 4;
#pragma unroll
        for (int jj = 0; jj < 4; ++jj) {
            int n = n0 + j4 + jj;
            tile[i][j4 + jj] = (k0 + i < 400 && n < 400) ? W2[(long)(k0 + i) * 400 + n] : 0.f;
        }
        __syncthreads();
        int o = t >> 3;
        if (n0 + o < 400) {
#pragma unroll
            for (int jj = 0; jj < 4; ++jj) {
                int k = k0 + j4 + jj;
                if (k < 400) W2t[(long)(n0 + o) * 400 + k] = f2bf(tile[j4 + jj][o]);
            }
        }
    } else if (blk < 594) {                // BbigT rows 500..999
        int gid = (blk - 494) * 256 + t;
        for (int g = gid; g < 50000; g += 100 * 256) {
            int n = g / 100, kq = (g % 100) * 4;
            ushort4 u;
            u.x = (kq + 0 < 200) ? f2bf(rel[(long)n * 200 + kq + 0]) : (u16)0;
            u.y = (kq + 1 < 200) ? f2bf(rel[(long)n * 200 + kq + 1]) : (u16)0;
            u.z = (kq + 2 < 200) ? f2bf(rel[(long)n * 200 + kq + 2]) : (u16)0;
            u.w = (kq + 3 < 200) ? f2bf(rel[(long)n * 200 + kq + 3]) : (u16)0;
            *(ushort4*)(BbigT + (long)(500 + n) * 400 + kq) = u;
        }
    } else if (blk == 594) {               // bbig3 = [brel | zeros]
        if (t < 200) bs[t] = batt[t];
        __syncthreads();
        for (int n = t; n < NRELS; n += 256) {
            const float* rr = rel + (long)n * RDIM;
            float s = 0.f;
            for (int k = 0; k < 200; ++k) s += bs[k] * rr[k];
            bbig3[n] = s;
        }
        for (int n = t; n < 500; n += 256) bbig3[500 + n] = 0.f;
    } else {                               // BbigT rows 0..499 (MFMA GEMM)
        int idx = blk - 595;               // 56 blocks: 8 bn x 7 bm
        int bn = (idx & 7) * 64, bm = (idx >> 3) * 64;
        mgemm_body<0, 0, 2, 0, 0>(Watt, rel, nullptr, nullptr, BbigT, 400,
                                  nullptr, nullptr, nullptr,
                                  400, 500, 200, bn, bm, 0, 1,
                                  nullptr, nullptr, nullptr, nullptr, nullptr,
                                  As, Bs, t);
    }
}

// ---------------------------------------------------------------------------
// k_scores: ent-gather dot (8 actions in flight, two-phase cross-lane
// reduction) + xr lookup + masked softmax + entropy + rel softmax.
// SX = [Srel_raw+brel (500) | X2rel (500)] fp32, final values.
// ---------------------------------------------------------------------------
__global__ __launch_bounds__(512) void k_scores(
    const float* __restrict__ X2, const float* __restrict__ SX,
    const int* __restrict__ r_space, const int* __restrict__ e_space,
    const int* __restrict__ amask,
    const float* __restrict__ ent_emb,
    float* __restrict__ out_dist, float* __restrict__ out_ent,
    float* __restrict__ out_rel)
{
    int b = blockIdx.x, t = threadIdx.x;
    int wave = t >> 6, lane = t & 63;
    __shared__ __align__(16) float4 xt4[50];   // X2[200:400]
    __shared__ float xr[NRELS];                // X2rel row
    __shared__ float sc[ASZ];
    __shared__ int   smask[ASZ];
    __shared__ float red[8];

    const float* rowX2 = X2 + (long)b * ACTDIM;
    const float* rowS  = SX + (long)b * 1000;
    if (t < 50) xt4[t] = *(const float4*)(rowX2 + 200 + 4 * t);
    for (int i = t; i < NRELS; i += 512) xr[i] = rowS[500 + i];

    int abase = wave * 32;
    int r_idx = 0, e_idx = 0, mk = 0;
    if (lane < 32) {
        long base = (long)b * ASZ + abase + lane;
        r_idx = r_space[base];
        e_idx = e_space[base];
        mk    = amask[base];
        smask[abase + lane] = mk;
    }
    __syncthreads();

    float4 x = (lane < 50) ? xt4[lane] : make_float4(0.f, 0.f, 0.f, 0.f);
    const int g = lane >> 4;

#pragma unroll
    for (int i = 0; i < 4; ++i) {              // 8 actions per iteration
        float s[8] = {0.f,0.f,0.f,0.f,0.f,0.f,0.f,0.f};
        int rj[8];
#pragma unroll
        for (int j = 0; j < 8; ++j) {
            int a = 8 * i + j;
            int m0 = __shfl(mk, a);
            rj[j]  = __shfl(r_idx, a);
            if (m0) {
                int e0 = __shfl(e_idx, a);
                if (lane < 50) {
                    float4 v = ((const float4*)(ent_emb + (long)e0 * EDIM))[lane];
                    s[j] = fmaf(v.x, x.x, fmaf(v.y, x.y, fmaf(v.z, x.z, v.w * x.w)));
                }
            }
        }
        // phase 1: fold 64 lanes -> 16-lane groups each holding full partials
#pragma unroll
        for (int j = 0; j < 8; ++j) {
            s[j] += __shfl_xor(s[j], 32);
            s[j] += __shfl_xor(s[j], 16);
        }
        // phase 2: group g finishes action g (and 4+g)
        float v0 = (g == 0) ? s[0] : (g == 1) ? s[1] : (g == 2) ? s[2] : s[3];
        float v1 = (g == 0) ? s[4] : (g == 1) ? s[5] : (g == 2) ? s[6] : s[7];
#pragma unroll
        for (int off = 8; off > 0; off >>= 1) {
            v0 += __shfl_xor(v0, off);
            v1 += __shfl_xor(v1, off);
        }
        int r0sel = (g == 0) ? rj[0] : (g == 1) ? rj[1] : (g == 2) ? rj[2] : rj[3];
        int r1sel = (g == 0) ? rj[4] : (g == 1) ? rj[5] : (g == 2) ? rj[6] : rj[7];
        if ((lane & 15) == 0) {
            sc[abase + 8 * i + g]     = v0 + xr[r0sel];
            sc[abase + 8 * i + 4 + g] = v1 + xr[r1sel];
        }
    }
    __syncthreads();

    // ---- masked softmax over 256 actions ----
    float v = -3.4e38f;
    float evv = 0.f;
    if (t < ASZ) v = smask[t] ? sc[t] : -1e31f;

    float m = v;
#pragma unroll
    for (int off = 32; off > 0; off >>= 1) m = fmaxf(m, __shfl_xor(m, off));
    if (t < ASZ && lane == 0) red[wave] = m;
    __syncthreads();
    float mm = fmaxf(fmaxf(red[0], red[1]), fmaxf(red[2], red[3]));
    __syncthreads();

    if (t < ASZ) evv = expf(v - mm);
    float ss = evv;
#pragma unroll
    for (int off = 32; off > 0; off >>= 1) ss += __shfl_xor(ss, off);
    if (t < ASZ && lane == 0) red[wave] = ss;
    __syncthreads();
    float tot = red[0] + red[1] + red[2] + red[3];
    __syncthreads();

    float term = 0.f;
    if (t < ASZ) {
        float p = evv / tot;
        out_dist[(long)b * ASZ + t] = p;
        term = p * logf(p + 1e-20f);
    }
#pragma unroll
    for (int off = 32; off > 0; off >>= 1) term += __shfl_xor(term, off);
    if (t < ASZ && lane == 0) red[wave] = term;
    __syncthreads();
    if (t == 0) out_ent[b] = -(red[0] + red[1] + red[2] + red[3]);
    __syncthreads();   // red[] reuse barrier

    // ---- relation-attention softmax over SX[b][0:500] (bias pre-applied) ----
    float rv = (t < NRELS) ? rowS[t] : -3.4e38f;

    float rm = rv;
#pragma unroll
    for (int off = 32; off > 0; off >>= 1) rm = fmaxf(rm, __shfl_xor(rm, off));
    if (lane == 0) red[wave] = rm;
    __syncthreads();
    rm = fmaxf(fmaxf(fmaxf(red[0], red[1]), fmaxf(red[2], red[3])),
               fmaxf(fmaxf(red[4], red[5]), fmaxf(red[6], red[7])));
    __syncthreads();

    float rev = (t < NRELS) ? expf(rv - rm) : 0.f;
    float rs = rev;
#pragma unroll
    for (int off = 32; off > 0; off >>= 1) rs += __shfl_xor(rs, off);
    if (lane == 0) red[wave] = rs;
    __syncthreads();
    rs = red[0] + red[1] + red[2] + red[3] + red[4] + red[5] + red[6] + red[7];
    if (t < NRELS) out_rel[(long)b * NRELS + t] = rev / rs;
}

// ---------------------------------------------------------------------------
extern "C" void kernel_launch(void* const* d_in, const int* in_sizes, int n_in,
                              void* d_out, int out_size, void* d_ws, size_t ws_size,
                              hipStream_t stream)
{
    const int*   e       = (const int*)  d_in[0];
    const int*   q       = (const int*)  d_in[1];
    const float* H       = (const float*)d_in[2];
    const int*   r_space = (const int*)  d_in[3];
    const int*   e_space = (const int*)  d_in[4];
    const int*   amask   = (const int*)  d_in[5];
    const float* ent     = (const float*)d_in[6];
    const float* rel     = (const float*)d_in[7];
    const float* W1      = (const float*)d_in[8];
    const float* b1      = (const float*)d_in[9];
    const float* W2      = (const float*)d_in[10];
    const float* b2      = (const float*)d_in[11];
    const float* Watt    = (const float*)d_in[12];
    const float* batt    = (const float*)d_in[13];

    float* out      = (float*)d_out;
    float* out_dist = out;                              // [1024,256]
    float* out_ent  = out + (long)BATCH * ASZ;          // [1024]
    float* out_rel  = out_ent + BATCH;                  // [1024,500]

    char* ws = (char*)d_ws;
    float* X2    = (float*)(ws + 0);            // 1024x400x4  = 1,638,400
    u16*   X2_bf = (u16*)  (ws + 1638400);      // 1024x400x2  =   819,200
    u16*   W1t   = (u16*)  (ws + 2457600);      // 400x800x2   =   640,000
    u16*   W2t   = (u16*)  (ws + 3097600);      // 400x400x2   =   320,000
    u16*   BbigT = (u16*)  (ws + 3417600);      // 1000x400x2  =   800,000
    float* bbig3 = (float*)(ws + 4217600);      // 1000x4      =     4,000
    float* SX    = (float*)(ws + 4221600);      // 1024x1000x4 = 4,096,000
    float* Cp    = (float*)(ws + 8317600);      // 4x1024x400x4 = 6,553,600

    // 1) all weight prep: W1t, W2t, BbigT (both halves), bbig3
    k_prep_all<<<651, 256, 0, stream>>>(W1, W2, batt, rel, Watt,
                                        W1t, W2t, BbigT, bbig3);

    // 2) X1 partials = [ent|H|rel] @ W1t^T  [1024,400] K=800, split-K 4, gather fused
    k_mgemm<1, 1, 1, 1, 0><<<dim3(7, 16, 4), 256, 0, stream>>>(
        nullptr, W1t, nullptr, Cp, nullptr, 0, nullptr, nullptr, nullptr,
        BATCH, ACTDIM, INDIM, e, q, H, ent, rel);

    // 3) X2 = relu_reduce(X1 partials)+b1 staged -> @ W2t^T + b2  (fp32 + bf16)
    //    A-staging does the 4-slab sum + b1 + relu + bf16 cvt (old k_reduce2).
    k_mgemm<2, 1, 3, 0, 0><<<dim3(7, 16, 1), 256, 0, stream>>>(
        Cp, W2t, b1, nullptr, nullptr, 0, b2, X2, X2_bf,
        BATCH, ACTDIM, ACTDIM, nullptr, nullptr, nullptr, nullptr, nullptr);

    // 4) SX = X2 @ BbigT^T + bbig3  [1024,1000] K=400, direct, final fp32
    k_mgemm<1, 1, 4, 0, 0><<<dim3(16, 16, 1), 256, 0, stream>>>(
        X2_bf, BbigT, nullptr, nullptr, nullptr, 0, bbig3, SX, nullptr,
        BATCH, 1000, ACTDIM, nullptr, nullptr, nullptr, nullptr, nullptr);

    // 5) scores + masked softmax + entropy + rel softmax
    k_scores<<<BATCH, 512, 0, stream>>>(X2, SX, r_space, e_space, amask,
                                        ent, out_dist, out_ent, out_rel);
}

// Round 11
// 80.271 us; speedup vs baseline: 1.1270x; 1.1270x over previous
//
#include <hip/hip_runtime.h>

#define BATCH   1024
#define ASZ     256
#define EDIM    200
#define RDIM    200
#define HDIM    400
#define ACTDIM  400   // E+R
#define INDIM   800   // E+H+R
#define NRELS   500

typedef __attribute__((ext_vector_type(8))) short short8v;   // 8 bf16 (4 VGPR)
typedef __attribute__((ext_vector_type(4))) float float4v;   // MFMA acc
typedef unsigned short u16;

__device__ __forceinline__ u16 f2bf(float f) {               // RNE fp32->bf16
    union { float f; unsigned u; } v; v.f = f;
    unsigned r = v.u + 0x7FFFu + ((v.u >> 16) & 1u);
    return (u16)(r >> 16);
}

// ---------------------------------------------------------------------------
// Shared MFMA GEMM body: C = A[M,K] @ B^T (B stored [N][K]).
// 256 thr = 4 waves; 64x64 tile; wave -> 32x32 (2x2 16x16x32 frags).
// Software-prefetched staging: step s+1's global loads issue right after the
// stage barrier, overlapping the MFMA block.
// CT=1: fp32 partials to Cp slab z.  CT=2: bf16 transposed write to CTout.
// CT=3: direct epilogue — bias (+relu) then fp32 Cf AND bf16 Cb.
// GAT=1: A is the virtual fp32 concat [ent[e]|H|rel[q]] (chunk-aligned).
// ---------------------------------------------------------------------------
template<int ABF, int BBF, int CT, int GAT, int RELU>
__device__ __forceinline__ void mgemm_body(
    const void* __restrict__ A, const void* __restrict__ B,
    float* __restrict__ Cp, u16* __restrict__ CTout, int ldct,
    const float* __restrict__ bias, float* __restrict__ Cf, u16* __restrict__ Cb,
    int M, int N, int K, int bn, int bm, int z, int nz,
    const int* e_s, const int* q_s,
    const float* __restrict__ Hm, const float* __restrict__ ent,
    const float* __restrict__ rel,
    short* As, short* Bs, int t)
{
    const int tot = (K + 31) >> 5;
    const int s0 = (z * tot) / nz, s1 = ((z + 1) * tot) / nz;

    const int lane = t & 63, w = t >> 6;
    const int l15 = lane & 15, l4 = lane >> 4;
    const int wr = (w >> 1) * 32, wc = (w & 1) * 32;

    const int row = t >> 2;          // staging row 0..63
    const int kc  = (t & 3) * 8;     // staging k-chunk

    auto loadA = [&](int s) -> uint4 {
        const int gk = (s << 5) + kc;
        __attribute__((aligned(16))) u16 v[8];
        if (GAT) {
            const float* p;
            if (gk < EDIM)              p = ent + (long)e_s[row] * EDIM + gk;
            else if (gk < EDIM + HDIM)  p = Hm  + (long)(bm + row) * HDIM + (gk - EDIM);
            else                        p = rel + (long)q_s[row] * RDIM + (gk - EDIM - HDIM);
            float4 f0 = *(const float4*)p;
            float4 f1 = *(const float4*)(p + 4);
            v[0]=f2bf(f0.x); v[1]=f2bf(f0.y); v[2]=f2bf(f0.z); v[3]=f2bf(f0.w);
            v[4]=f2bf(f1.x); v[5]=f2bf(f1.y); v[6]=f2bf(f1.z); v[7]=f2bf(f1.w);
            return *(uint4*)v;
        }
        const int gr = bm + row;
        if (gr < M && gk + 8 <= K) {
            if (ABF) return *(const uint4*)((const u16*)A + (long)gr * K + gk);
            const float* p = (const float*)A + (long)gr * K + gk;
            float4 f0 = *(const float4*)p;
            float4 f1 = *(const float4*)(p + 4);
            v[0]=f2bf(f0.x); v[1]=f2bf(f0.y); v[2]=f2bf(f0.z); v[3]=f2bf(f0.w);
            v[4]=f2bf(f1.x); v[5]=f2bf(f1.y); v[6]=f2bf(f1.z); v[7]=f2bf(f1.w);
            return *(uint4*)v;
        }
#pragma unroll
        for (int i = 0; i < 8; ++i) v[i] = 0;
        return *(uint4*)v;
    };
    auto loadB = [&](int s) -> uint4 {
        const int gk = (s << 5) + kc;
        const int gr = bn + row;
        __attribute__((aligned(16))) u16 v[8];
        if (gr < N && gk + 8 <= K) {
            if (BBF) return *(const uint4*)((const u16*)B + (long)gr * K + gk);
            const float* p = (const float*)B + (long)gr * K + gk;
            float4 f0 = *(const float4*)p;
            float4 f1 = *(const float4*)(p + 4);
            v[0]=f2bf(f0.x); v[1]=f2bf(f0.y); v[2]=f2bf(f0.z); v[3]=f2bf(f0.w);
            v[4]=f2bf(f1.x); v[5]=f2bf(f1.y); v[6]=f2bf(f1.z); v[7]=f2bf(f1.w);
            return *(uint4*)v;
        }
#pragma unroll
        for (int i = 0; i < 8; ++i) v[i] = 0;
        return *(uint4*)v;
    };

    float4v acc00 = {0.f,0.f,0.f,0.f}, acc01 = {0.f,0.f,0.f,0.f};
    float4v acc10 = {0.f,0.f,0.f,0.f}, acc11 = {0.f,0.f,0.f,0.f};

    uint4 ra = loadA(s0);
    uint4 rb = loadB(s0);

    for (int s = s0; s < s1; ++s) {
        *(uint4*)&As[row * 40 + kc] = ra;
        *(uint4*)&Bs[row * 40 + kc] = rb;
        __syncthreads();
        if (s + 1 < s1) {               // prefetch overlaps MFMA + barrier
            ra = loadA(s + 1);
            rb = loadB(s + 1);
        }
        short8v a0 = *(short8v*)&As[(wr      + l15) * 40 + l4 * 8];
        short8v a1 = *(short8v*)&As[(wr + 16 + l15) * 40 + l4 * 8];
        short8v b0 = *(short8v*)&Bs[(wc      + l15) * 40 + l4 * 8];
        short8v b1 = *(short8v*)&Bs[(wc + 16 + l15) * 40 + l4 * 8];
        acc00 = __builtin_amdgcn_mfma_f32_16x16x32_bf16(a0, b0, acc00, 0, 0, 0);
        acc01 = __builtin_amdgcn_mfma_f32_16x16x32_bf16(a0, b1, acc01, 0, 0, 0);
        acc10 = __builtin_amdgcn_mfma_f32_16x16x32_bf16(a1, b0, acc10, 0, 0, 0);
        acc11 = __builtin_amdgcn_mfma_f32_16x16x32_bf16(a1, b1, acc11, 0, 0, 0);
        __syncthreads();
    }

    const int rm0 = bm + wr + l4 * 4;
    const int cn0 = bn + wc + l15;
    if (CT == 1) {
        float* dst = Cp + (long)z * M * N;
#pragma unroll
        for (int r = 0; r < 4; ++r) {
            int gm0 = rm0 + r, gm1 = rm0 + 16 + r;
            if (gm0 < M) {
                if (cn0 < N)      dst[(long)gm0 * N + cn0]      = acc00[r];
                if (cn0 + 16 < N) dst[(long)gm0 * N + cn0 + 16] = acc01[r];
            }
            if (gm1 < M) {
                if (cn0 < N)      dst[(long)gm1 * N + cn0]      = acc10[r];
                if (cn0 + 16 < N) dst[(long)gm1 * N + cn0 + 16] = acc11[r];
            }
        }
    } else if (CT == 2) {
#pragma unroll
        for (int r = 0; r < 4; ++r) {
            int gm0 = rm0 + r, gm1 = rm0 + 16 + r;
            if (gm0 < M) {
                if (cn0 < N)      CTout[(long)cn0 * ldct + gm0]        = f2bf(acc00[r]);
                if (cn0 + 16 < N) CTout[(long)(cn0 + 16) * ldct + gm0] = f2bf(acc01[r]);
            }
            if (gm1 < M) {
                if (cn0 < N)      CTout[(long)cn0 * ldct + gm1]        = f2bf(acc10[r]);
                if (cn0 + 16 < N) CTout[(long)(cn0 + 16) * ldct + gm1] = f2bf(acc11[r]);
            }
        }
    } else {                            // CT==3: direct bias(+relu), dual output
        float bv0 = (cn0 < N)      ? bias[cn0]      : 0.f;
        float bv1 = (cn0 + 16 < N) ? bias[cn0 + 16] : 0.f;
#pragma unroll
        for (int r = 0; r < 4; ++r) {
            int gm0 = rm0 + r, gm1 = rm0 + 16 + r;
            if (gm0 < M) {
                if (cn0 < N) {
                    float v = acc00[r] + bv0;
                    if (RELU) v = fmaxf(v, 0.f);
                    Cf[(long)gm0 * N + cn0] = v;
                    Cb[(long)gm0 * N + cn0] = f2bf(v);
                }
                if (cn0 + 16 < N) {
                    float v = acc01[r] + bv1;
                    if (RELU) v = fmaxf(v, 0.f);
                    Cf[(long)gm0 * N + cn0 + 16] = v;
                    Cb[(long)gm0 * N + cn0 + 16] = f2bf(v);
                }
            }
            if (gm1 < M) {
                if (cn0 < N) {
                    float v = acc10[r] + bv0;
                    if (RELU) v = fmaxf(v, 0.f);
                    Cf[(long)gm1 * N + cn0] = v;
                    Cb[(long)gm1 * N + cn0] = f2bf(v);
                }
                if (cn0 + 16 < N) {
                    float v = acc11[r] + bv1;
                    if (RELU) v = fmaxf(v, 0.f);
                    Cf[(long)gm1 * N + cn0 + 16] = v;
                    Cb[(long)gm1 * N + cn0 + 16] = f2bf(v);
                }
            }
        }
    }
}

// ---------------------------------------------------------------------------
// k_mgemm kernel wrapper (grid: bn, bm, z)
// ---------------------------------------------------------------------------
template<int ABF, int BBF, int CT, int GAT, int RELU>
__global__ __launch_bounds__(256) void k_mgemm(
    const void* __restrict__ A, const void* __restrict__ B,
    float* __restrict__ Cp, u16* __restrict__ CTout, int ldct,
    const float* __restrict__ bias, float* __restrict__ Cf, u16* __restrict__ Cb,
    int M, int N, int K,
    const int* __restrict__ eidx, const int* __restrict__ qidx,
    const float* __restrict__ Hm, const float* __restrict__ ent,
    const float* __restrict__ rel)
{
    __shared__ __align__(16) short As[64 * 40];
    __shared__ __align__(16) short Bs[64 * 40];
    __shared__ int e_s[64], q_s[64];
    const int t = threadIdx.x;
    const int bm = blockIdx.y * 64;
    if (GAT) {
        if (t < 64) {
            e_s[t] = eidx[bm + t];
            q_s[t] = qidx[bm + t];
        }
        __syncthreads();
    }
    mgemm_body<ABF, BBF, CT, GAT, RELU>(A, B, Cp, CTout, ldct, bias, Cf, Cb,
                                        M, N, K, blockIdx.x * 64, bm,
                                        blockIdx.z, gridDim.z,
                                        e_s, q_s, Hm, ent, rel, As, Bs, t);
}

// ---------------------------------------------------------------------------
// k_prep_all: blocks 0..324  W1[800,400] -> W1t[400,800] bf16 (transpose)
//             blocks 325..493 W2[400,400] -> W2t[400,400] bf16 (transpose)
//             blocks 494..593 BbigT rows 500..999 = [rel_bf16 | zeros]
//             block  594      bbig2[0:500] = batt @ rel^T
//             blocks 595..650 BbigT rows 0..499 = (Watt @ rel^T)^T  (MFMA GEMM)
// ---------------------------------------------------------------------------
__global__ __launch_bounds__(256) void k_prep_all(
    const float* __restrict__ W1, const float* __restrict__ W2,
    const float* __restrict__ batt, const float* __restrict__ rel,
    const float* __restrict__ Watt,
    u16* __restrict__ W1t, u16* __restrict__ W2t,
    u16* __restrict__ BbigT, float* __restrict__ bbig2)
{
    __shared__ __align__(16) short As[64 * 40];
    __shared__ __align__(16) short Bs[64 * 40];
    __shared__ float tile[32][33];
    __shared__ float bs[200];

    int blk = blockIdx.x, t = threadIdx.x;

    if (blk < 325) {                       // W1 transpose: 25 k-tiles x 13 n-tiles
        int tk = blk / 13, tn = blk % 13;
        int k0 = tk * 32, n0 = tn * 32;
        int i = t >> 3, j4 = (t & 7) * 4;
#pragma unroll
        for (int jj = 0; jj < 4; ++jj) {
            int n = n0 + j4 + jj;
            tile[i][j4 + jj] = (n < 400) ? W1[(long)(k0 + i) * 400 + n] : 0.f;
        }
        __syncthreads();
        int o = t >> 3;
        if (n0 + o < 400) {
            ushort4 u;
            u.x = f2bf(tile[j4 + 0][o]); u.y = f2bf(tile[j4 + 1][o]);
            u.z = f2bf(tile[j4 + 2][o]); u.w = f2bf(tile[j4 + 3][o]);
            *(ushort4*)(W1t + (long)(n0 + o) * 800 + k0 + j4) = u;
        }
    } else if (blk < 494) {                // W2 transpose: 13 x 13
        int idx = blk - 325;
        int tk = idx / 13, tn = idx % 13;
        int k0 = tk * 32, n0 = tn * 32;
        int i = t >> 3, j4 = (t & 7) * 4;
#pragma unroll
        for (int jj = 0; jj < 4; ++jj) {
            int n = n0 + j4 + jj;
            tile[i][j4 + jj] = (k0 + i < 400 && n < 400) ? W2[(long)(k0 + i) * 400 + n] : 0.f;
        }
        __syncthreads();
        int o = t >> 3;
        if (n0 + o < 400 && k0 + j4 + 4 <= 400) {   // vectorized (valid chunks are fully in-bounds)
            ushort4 u;
            u.x = f2bf(tile[j4 + 0][o]); u.y = f2bf(tile[j4 + 1][o]);
            u.z = f2bf(tile[j4 + 2][o]); u.w = f2bf(tile[j4 + 3][o]);
            *(ushort4*)(W2t + (long)(n0 + o) * 400 + k0 + j4) = u;
        }
    } else if (blk < 594) {                // BbigT rows 500..999
        int gid = (blk - 494) * 256 + t;
        for (int g = gid; g < 50000; g += 100 * 256) {
            int n = g / 100, kq = (g % 100) * 4;
            ushort4 u;
            u.x = (kq + 0 < 200) ? f2bf(rel[(long)n * 200 + kq + 0]) : (u16)0;
            u.y = (kq + 1 < 200) ? f2bf(rel[(long)n * 200 + kq + 1]) : (u16)0;
            u.z = (kq + 2 < 200) ? f2bf(rel[(long)n * 200 + kq + 2]) : (u16)0;
            u.w = (kq + 3 < 200) ? f2bf(rel[(long)n * 200 + kq + 3]) : (u16)0;
            *(ushort4*)(BbigT + (long)(500 + n) * 400 + kq) = u;
        }
    } else if (blk == 594) {               // brel = batt @ rel^T
        if (t < 200) bs[t] = batt[t];
        __syncthreads();
        for (int n = t; n < NRELS; n += 256) {
            const float* rr = rel + (long)n * RDIM;
            float s = 0.f;
            for (int k = 0; k < 200; ++k) s += bs[k] * rr[k];
            bbig2[n] = s;
        }
    } else {                               // BbigT rows 0..499 (MFMA GEMM)
        int idx = blk - 595;               // 56 blocks: 8 bn x 7 bm
        int bn = (idx & 7) * 64, bm = (idx >> 3) * 64;
        mgemm_body<0, 0, 2, 0, 0>(Watt, rel, nullptr, BbigT, 400,
                                  nullptr, nullptr, nullptr,
                                  400, 500, 200, bn, bm, 0, 1,
                                  nullptr, nullptr, nullptr, nullptr, nullptr,
                                  As, Bs, t);
    }
}

// ---------------------------------------------------------------------------
// Split-K reduce (+bias, relu). OUT: 0=fp32 only, 1=bf16 only, 2=both.
// ---------------------------------------------------------------------------
template<int RELU, int OUT>
__global__ __launch_bounds__(128) void k_reduce2(
    const float* __restrict__ Cp, const float* __restrict__ bias,
    float* __restrict__ Cf, u16* __restrict__ Cb, int M, int N, int nks)
{
    int m = blockIdx.x;
    int nf4 = N >> 2;
    for (int f = threadIdx.x; f < nf4; f += 128) {
        long off = (long)m * N + f * 4;
        float4 s = *(const float4*)(Cp + off);
        for (int ks = 1; ks < nks; ++ks) {
            float4 v = *(const float4*)(Cp + (long)ks * M * N + off);
            s.x += v.x; s.y += v.y; s.z += v.z; s.w += v.w;
        }
        float4 bb = *(const float4*)(bias + f * 4);
        s.x += bb.x; s.y += bb.y; s.z += bb.z; s.w += bb.w;
        if (RELU) {
            s.x = fmaxf(s.x, 0.f); s.y = fmaxf(s.y, 0.f);
            s.z = fmaxf(s.z, 0.f); s.w = fmaxf(s.w, 0.f);
        }
        if (OUT != 1) *(float4*)(Cf + off) = s;
        if (OUT != 0) {
            ushort4 u;
            u.x = f2bf(s.x); u.y = f2bf(s.y); u.z = f2bf(s.z); u.w = f2bf(s.w);
            *(ushort4*)(Cb + off) = u;
        }
    }
}

// ---------------------------------------------------------------------------
// k_scores: fused SX split-K reduce + ent-gather dot (8 actions in flight,
// two-phase cross-lane reduction) + masked softmax + entropy + rel softmax.
// ---------------------------------------------------------------------------
__global__ __launch_bounds__(512) void k_scores(
    const float* __restrict__ X2, const float* __restrict__ Cp,
    const float* __restrict__ brel,
    const int* __restrict__ r_space, const int* __restrict__ e_space,
    const int* __restrict__ amask,
    const float* __restrict__ ent_emb,
    float* __restrict__ out_dist, float* __restrict__ out_ent,
    float* __restrict__ out_rel)
{
    int b = blockIdx.x, t = threadIdx.x;
    int wave = t >> 6, lane = t & 63;
    __shared__ __align__(16) float4 xt4[50];   // X2[200:400]
    __shared__ float xr[NRELS];                // X2rel row
    __shared__ float sc[ASZ];
    __shared__ int   smask[ASZ];
    __shared__ float red[8];

    const float* rowX2 = X2 + (long)b * ACTDIM;
    const float* c0 = Cp + (long)b * 1000;
    const float* c1 = Cp + (long)BATCH * 1000 + (long)b * 1000;
    if (t < 50) xt4[t] = *(const float4*)(rowX2 + 200 + 4 * t);
    for (int i = t; i < NRELS; i += 512) xr[i] = c0[500 + i] + c1[500 + i];

    int abase = wave * 32;
    int r_idx = 0, e_idx = 0, mk = 0;
    if (lane < 32) {
        long base = (long)b * ASZ + abase + lane;
        r_idx = r_space[base];
        e_idx = e_space[base];
        mk    = amask[base];
        smask[abase + lane] = mk;
    }
    __syncthreads();

    float4 x = (lane < 50) ? xt4[lane] : make_float4(0.f, 0.f, 0.f, 0.f);
    const int g = lane >> 4;

#pragma unroll
    for (int i = 0; i < 4; ++i) {              // 8 actions per iteration
        float s[8] = {0.f,0.f,0.f,0.f,0.f,0.f,0.f,0.f};
        int rj[8];
#pragma unroll
        for (int j = 0; j < 8; ++j) {
            int a = 8 * i + j;
            int m0 = __shfl(mk, a);
            rj[j]  = __shfl(r_idx, a);
            if (m0) {
                int e0 = __shfl(e_idx, a);
                if (lane < 50) {
                    float4 v = ((const float4*)(ent_emb + (long)e0 * EDIM))[lane];
                    s[j] = fmaf(v.x, x.x, fmaf(v.y, x.y, fmaf(v.z, x.z, v.w * x.w)));
                }
            }
        }
        // phase 1: fold 64 lanes -> 16-lane groups each holding full partials
#pragma unroll
        for (int j = 0; j < 8; ++j) {
            s[j] += __shfl_xor(s[j], 32);
            s[j] += __shfl_xor(s[j], 16);
        }
        // phase 2: group g finishes action g (and 4+g)
        float v0 = (g == 0) ? s[0] : (g == 1) ? s[1] : (g == 2) ? s[2] : s[3];
        float v1 = (g == 0) ? s[4] : (g == 1) ? s[5] : (g == 2) ? s[6] : s[7];
#pragma unroll
        for (int off = 8; off > 0; off >>= 1) {
            v0 += __shfl_xor(v0, off);
            v1 += __shfl_xor(v1, off);
        }
        int r0sel = (g == 0) ? rj[0] : (g == 1) ? rj[1] : (g == 2) ? rj[2] : rj[3];
        int r1sel = (g == 0) ? rj[4] : (g == 1) ? rj[5] : (g == 2) ? rj[6] : rj[7];
        if ((lane & 15) == 0) {
            sc[abase + 8 * i + g]     = v0 + xr[r0sel];
            sc[abase + 8 * i + 4 + g] = v1 + xr[r1sel];
        }
    }
    __syncthreads();

    // ---- masked softmax over 256 actions ----
    float v = -3.4e38f;
    float evv = 0.f;
    if (t < ASZ) v = smask[t] ? sc[t] : -1e31f;

    float m = v;
#pragma unroll
    for (int off = 32; off > 0; off >>= 1) m = fmaxf(m, __shfl_xor(m, off));
    if (t < ASZ && lane == 0) red[wave] = m;
    __syncthreads();
    float mm = fmaxf(fmaxf(red[0], red[1]), fmaxf(red[2], red[3]));
    __syncthreads();

    if (t < ASZ) evv = expf(v - mm);
    float ss = evv;
#pragma unroll
    for (int off = 32; off > 0; off >>= 1) ss += __shfl_xor(ss, off);
    if (t < ASZ && lane == 0) red[wave] = ss;
    __syncthreads();
    float tot = red[0] + red[1] + red[2] + red[3];
    __syncthreads();

    float term = 0.f;
    if (t < ASZ) {
        float p = evv / tot;
        out_dist[(long)b * ASZ + t] = p;
        term = p * logf(p + 1e-20f);
    }
#pragma unroll
    for (int off = 32; off > 0; off >>= 1) term += __shfl_xor(term, off);
    if (t < ASZ && lane == 0) red[wave] = term;
    __syncthreads();
    if (t == 0) out_ent[b] = -(red[0] + red[1] + red[2] + red[3]);
    __syncthreads();   // red[] reuse barrier

    // ---- relation-attention softmax: raw = c0+c1+brel ----
    float rv = (t < NRELS) ? (c0[t] + c1[t] + brel[t]) : -3.4e38f;

    float rm = rv;
#pragma unroll
    for (int off = 32; off > 0; off >>= 1) rm = fmaxf(rm, __shfl_xor(rm, off));
    if (lane == 0) red[wave] = rm;
    __syncthreads();
    rm = fmaxf(fmaxf(fmaxf(red[0], red[1]), fmaxf(red[2], red[3])),
               fmaxf(fmaxf(red[4], red[5]), fmaxf(red[6], red[7])));
    __syncthreads();

    float rev = (t < NRELS) ? expf(rv - rm) : 0.f;
    float rs = rev;
#pragma unroll
    for (int off = 32; off > 0; off >>= 1) rs += __shfl_xor(rs, off);
    if (lane == 0) red[wave] = rs;
    __syncthreads();
    rs = red[0] + red[1] + red[2] + red[3] + red[4] + red[5] + red[6] + red[7];
    if (t < NRELS) out_rel[(long)b * NRELS + t] = rev / rs;
}

// ---------------------------------------------------------------------------
extern "C" void kernel_launch(void* const* d_in, const int* in_sizes, int n_in,
                              void* d_out, int out_size, void* d_ws, size_t ws_size,
                              hipStream_t stream)
{
    const int*   e       = (const int*)  d_in[0];
    const int*   q       = (const int*)  d_in[1];
    const float* H       = (const float*)d_in[2];
    const int*   r_space = (const int*)  d_in[3];
    const int*   e_space = (const int*)  d_in[4];
    const int*   amask   = (const int*)  d_in[5];
    const float* ent     = (const float*)d_in[6];
    const float* rel     = (const float*)d_in[7];
    const float* W1      = (const float*)d_in[8];
    const float* b1      = (const float*)d_in[9];
    const float* W2      = (const float*)d_in[10];
    const float* b2      = (const float*)d_in[11];
    const float* Watt    = (const float*)d_in[12];
    const float* batt    = (const float*)d_in[13];

    float* out      = (float*)d_out;
    float* out_dist = out;                              // [1024,256]
    float* out_ent  = out + (long)BATCH * ASZ;          // [1024]
    float* out_rel  = out_ent + BATCH;                  // [1024,500]

    char* ws = (char*)d_ws;
    u16*   X1_bf  = (u16*)  (ws + 0);           // 1024x400x2  =   819,200
    float* X2     = (float*)(ws + 819200);      // 1024x400x4  = 1,638,400
    u16*   X2_bf  = (u16*)  (ws + 2457600);     // 1024x400x2  =   819,200
    u16*   W1t    = (u16*)  (ws + 3276800);     // 400x800x2   =   640,000
    u16*   W2t    = (u16*)  (ws + 3916800);     // 400x400x2   =   320,000
    u16*   BbigT  = (u16*)  (ws + 4236800);     // 1000x400x2  =   800,000
    float* bbig2  = (float*)(ws + 5036800);     // 500x4       =     2,000
    float* Cp     = (float*)(ws + 5242880);     // up to 8,192,000 (split-K)

    // 1) all weight prep: W1t, W2t, BbigT (both halves), brel
    k_prep_all<<<651, 256, 0, stream>>>(W1, W2, batt, rel, Watt,
                                        W1t, W2t, BbigT, bbig2);

    // 2) X1 = relu([ent|H|rel] @ W1 + b1)  [1024,400] K=800, split-K 4, gather fused
    k_mgemm<1, 1, 1, 1, 0><<<dim3(7, 16, 4), 256, 0, stream>>>(
        nullptr, W1t, Cp, nullptr, 0, nullptr, nullptr, nullptr,
        BATCH, ACTDIM, INDIM, e, q, H, ent, rel);
    k_reduce2<1, 1><<<BATCH, 128, 0, stream>>>(Cp, b1, nullptr, X1_bf, BATCH, ACTDIM, 4);

    // 3) X2 = X1 @ W2 + b2  [1024,400] K=400, direct epilogue (fp32 + bf16)
    k_mgemm<1, 1, 3, 0, 0><<<dim3(7, 16, 1), 256, 0, stream>>>(
        X1_bf, W2t, nullptr, nullptr, 0, b2, X2, X2_bf,
        BATCH, ACTDIM, ACTDIM, nullptr, nullptr, nullptr, nullptr, nullptr);

    // 4) SX partials = X2 @ BbigT^T  [1024,1000] K=400, split-K 2 (reduce in k_scores)
    k_mgemm<1, 1, 1, 0, 0><<<dim3(16, 16, 2), 256, 0, stream>>>(
        X2_bf, BbigT, Cp, nullptr, 0, nullptr, nullptr, nullptr,
        BATCH, 1000, ACTDIM, nullptr, nullptr, nullptr, nullptr, nullptr);

    // 5) scores + SX reduce + masked softmax + entropy + rel softmax
    k_scores<<<BATCH, 512, 0, stream>>>(X2, Cp, bbig2, r_space, e_space, amask,
                                        ent, out_dist, out_ent, out_rel);
}